// Round 3
// baseline (373.608 us; speedup 1.0000x reference)
//
#include <hip/hip_runtime.h>

constexpr int BATCH = 1000000;
constexpr int NBINS = 37;
constexpr int TPB = 256;
constexpr int TILE_ROWS = 256;
constexpr int TILE_FLOATS = TILE_ROWS * NBINS;   // 9472 floats = 37888 B
constexpr int NV_FULL = TILE_FLOATS / 4;         // 2368 float4 per tile
constexpr float NEG_BIG = -1e30f;
constexpr float LOGCLAMP = -100.0f;

__global__ __launch_bounds__(TPB, 4)
void adviser_loss_kernel(const float* __restrict__ preds,
                         const float* __restrict__ labels,
                         const float* __restrict__ weights,
                         const int* __restrict__ obj_classes,
                         float* __restrict__ out)
{
    __shared__ float tile[TILE_FLOATS];
    __shared__ float cls_sum[3];

    const int tid   = threadIdx.x;
    const int row0  = blockIdx.x * TILE_ROWS;
    const int nrows = min(TILE_ROWS, BATCH - row0);
    const bool full = (nrows == TILE_ROWS);
    const int nvec  = (nrows * NBINS) >> 2;      // rows%4==0 always

    if (tid < 3) cls_sum[tid] = 0.0f;

    // class + weight (clamped index for tail-block invalid threads)
    const int   crow = min(row0 + tid, BATCH - 1);
    const int   c    = obj_classes[crow];
    const float w    = weights[c];

    // ---- preds tile -> LDS via global_load_lds (no VGPR round trip) ----
    // Guards are wave-uniform (k=9 covers exactly tid<64 = one full wave).
    const float4* gp = (const float4*)(preds + (size_t)row0 * NBINS);
    if (full) {
        #pragma unroll
        for (int k = 0; k < 10; ++k) {
            const int i = tid + k * TPB;
            if (i < NV_FULL)
                __builtin_amdgcn_global_load_lds(
                    (const __attribute__((address_space(1))) void*)(gp + i),
                    (__attribute__((address_space(3))) void*)(&tile[i * 4]),
                    16, 0, 0);
        }
    } else {
        for (int i = tid; i < nvec; i += TPB)
            ((float4*)tile)[i] = gp[i];
    }

    // ---- labels tile -> registers, in flight concurrently with preds ----
    const float4* gl = (const float4*)(labels + (size_t)row0 * NBINS);
    float4 lv4[10];   // const-indexed only (stays in VGPRs)
    #pragma unroll
    for (int k = 0; k < 10; ++k) {
        const int i = tid + k * TPB;
        if (i < nvec) lv4[k] = gl[i];
    }

    __syncthreads();   // drains vmcnt: preds tile (and label regs) ready

    const bool valid = (tid < nrows);
    const int  s     = 13 * c;               // slice start 0/13/26
    const int  L     = (c == 2) ? 11 : 13;   // slice len 13/13/11
    const int  base  = tid * NBINS + s;      // (j<L) keeps all reads in-bounds

    // ---- preds softmax over slice; no max pass (|preds|<7 -> no overflow) ----
    float pv[13], ep[13];
    #pragma unroll
    for (int j = 0; j < 13; ++j)
        pv[j] = (j < L) ? tile[base + j] : NEG_BIG;
    float Z = 0.0f;
    #pragma unroll
    for (int j = 0; j < 13; ++j) { ep[j] = __expf(pv[j]); Z += ep[j]; }

    __syncthreads();   // everyone done reading preds tile

    // ---- labels regs -> LDS (same buffer) ----
    #pragma unroll
    for (int k = 0; k < 10; ++k) {
        const int i = tid + k * TPB;
        if (i < nvec) ((float4*)tile)[i] = lv4[k];
    }
    __syncthreads();

    float et[13];
    float Zt = 0.0f;
    #pragma unroll
    for (int j = 0; j < 13; ++j) {
        const float lv = (j < L) ? tile[base + j] : NEG_BIG;
        et[j] = __expf(lv);
        Zt += et[j];
    }

    const float logZ  = __logf(Z);
    const float rcpZ  = __builtin_amdgcn_rcpf(Z);
    const float rcpZt = __builtin_amdgcn_rcpf(Zt);

    // ---- fused BCE: -(t*clamp(logp) + (1-t)*clamp(log(1-p))) ----
    float acc = 0.0f;
    #pragma unroll
    for (int j = 0; j < 13; ++j) {
        const float logp = pv[j] - logZ;                 // masked j -> -1e30
        const float p    = ep[j] * rcpZ;                 // masked j -> 0
        const float ca   = fmaxf(logp, LOGCLAMP);
        const float cb   = fmaxf(__logf(fmaxf(1.0f - p, 0.0f)), LOGCLAMP);
        const float t    = et[j] * rcpZt;                // masked j -> 0
        acc += cb + t * (ca - cb);                       // = t*ca + (1-t)*cb
    }
    const float per_sample = valid ? (-acc) * w : 0.0f;  // kills tail garbage/NaN

    // ---- reduce: per-class wave shuffle -> LDS atomics -> global atomics ----
    float v0 = (c == 0) ? per_sample : 0.0f;
    float v1 = (c == 1) ? per_sample : 0.0f;
    float v2 = (c == 2) ? per_sample : 0.0f;
    #pragma unroll
    for (int off = 32; off > 0; off >>= 1) {
        v0 += __shfl_down(v0, off, 64);
        v1 += __shfl_down(v1, off, 64);
        v2 += __shfl_down(v2, off, 64);
    }
    if ((tid & 63) == 0) {
        atomicAdd(&cls_sum[0], v0);
        atomicAdd(&cls_sum[1], v1);
        atomicAdd(&cls_sum[2], v2);
    }
    __syncthreads();
    if (tid < 3) atomicAdd(&out[1 + tid], cls_sum[tid]);
    if (tid == 0)
        atomicAdd(&out[0], (cls_sum[0] + cls_sum[1] + cls_sum[2]) * (1.0f / (float)BATCH));
}

extern "C" void kernel_launch(void* const* d_in, const int* in_sizes, int n_in,
                              void* d_out, int out_size, void* d_ws, size_t ws_size,
                              hipStream_t stream) {
    const float* preds   = (const float*)d_in[0];
    const float* labels  = (const float*)d_in[1];
    const float* weights = (const float*)d_in[2];
    const int*   obj     = (const int*)d_in[3];
    float* out = (float*)d_out;

    hipMemsetAsync(out, 0, (size_t)out_size * sizeof(float), stream);
    const int grid = (BATCH + TILE_ROWS - 1) / TILE_ROWS;
    adviser_loss_kernel<<<grid, TPB, 0, stream>>>(preds, labels, weights, obj, out);
}

// Round 5
// 331.742 us; speedup vs baseline: 1.1262x; 1.1262x over previous
//
#include <hip/hip_runtime.h>

constexpr int BATCH  = 1000000;
constexpr int NBINS  = 37;
constexpr int TPB    = 128;
constexpr int ROWS   = 128;               // rows per tile
constexpr int TFLOAT = ROWS * NBINS;      // 4736 floats per tensor-tile
constexpr int TVEC   = TFLOAT / 4;        // 1184 float4
constexpr int KFULL  = TVEC / TPB;        // 9 uniform gload_lds iters
constexpr int VREM   = TVEC - KFULL*TPB;  // 32 remainder float4 (reg-copied)
constexpr int NTILES = (BATCH + ROWS - 1) / ROWS;  // 7813
constexpr int NBLK   = 512;               // 2 blocks/CU (LDS-limited)
constexpr int QT     = NTILES / NBLK;     // 15
constexpr int RT     = NTILES % NBLK;     // 133
constexpr float NEG_BIG  = -1e30f;
constexpr float LOGCLAMP = -100.0f;

__global__ __launch_bounds__(TPB, 1)
void adviser_loss_kernel(const float* __restrict__ preds,
                         const float* __restrict__ labels,
                         const float* __restrict__ weights,
                         const int* __restrict__ obj,
                         float* __restrict__ out)
{
    __shared__ float buf[2][2][TFLOAT];   // [buffer][preds/labels][tile]
    __shared__ float cls_sum[3];

    const int tid = threadIdx.x;
    const int b   = blockIdx.x;
    if (tid < 3) cls_sum[tid] = 0.0f;

    const int cnt = QT + (b < RT ? 1 : 0);
    const int t0  = b * QT + min(b, RT);

    const float w0 = weights[0], w1 = weights[1], w2 = weights[2];

    auto stage = [&](int sel, int t) {
        const int rowbase = t * ROWS;
        const int nrows   = min(ROWS, BATCH - rowbase);
        const float4* gp = (const float4*)(preds  + (size_t)rowbase * NBINS);
        const float4* gl = (const float4*)(labels + (size_t)rowbase * NBINS);
        if (nrows == ROWS) {
            #pragma unroll
            for (int k = 0; k < KFULL; ++k) {     // wave-uniform, unconditional
                const int i = tid + k * TPB;
                __builtin_amdgcn_global_load_lds(
                    (const __attribute__((address_space(1))) void*)(gp + i),
                    (__attribute__((address_space(3))) void*)(&buf[sel][0][i * 4]),
                    16, 0, 0);
                __builtin_amdgcn_global_load_lds(
                    (const __attribute__((address_space(1))) void*)(gl + i),
                    (__attribute__((address_space(3))) void*)(&buf[sel][1][i * 4]),
                    16, 0, 0);
            }
            if (tid < VREM) {                     // 512 B remainder, plain copy
                const int i = KFULL * TPB + tid;
                ((float4*)buf[sel][0])[i] = gp[i];
                ((float4*)buf[sel][1])[i] = gl[i];
            }
        } else {                                  // tail tile (64 rows), once
            const int nv = (nrows * NBINS) >> 2;
            for (int i = tid; i < nv; i += TPB) {
                ((float4*)buf[sel][0])[i] = gp[i];
                ((float4*)buf[sel][1])[i] = gl[i];
            }
        }
    };

    // ---- prologue: stage tile t0 into buf[0] ----
    stage(0, t0);
    int ccur = obj[min(t0 * ROWS + tid, BATCH - 1)];
    __syncthreads();                              // stage(t0) complete

    float a0 = 0.0f, a1 = 0.0f, a2 = 0.0f;
    int cur = 0;

    for (int ti = 0; ti < cnt; ++ti) {
        const int t       = t0 + ti;
        const int rowbase = t * ROWS;
        const int nrows   = min(ROWS, BATCH - rowbase);

        // ---- issue next tile's stage FIRST (overlaps compute below) ----
        int cnext = ccur;
        if (ti + 1 < cnt) {
            stage(cur ^ 1, t + 1);
            cnext = obj[min((t + 1) * ROWS + tid, BATCH - 1)];
        }

        // ---- compute tile t from buf[cur] ----
        const bool valid = (tid < nrows);
        const int   c = ccur;
        const float w = (c == 0) ? w0 : ((c == 1) ? w1 : w2);
        const int   s = 13 * c;                   // slice start 0/13/26
        const int   L = (c == 2) ? 11 : 13;       // slice len (keeps LDS reads in-bounds)
        const int   base = tid * NBINS + s;

        const float* P = buf[cur][0];
        const float* T = buf[cur][1];

        float pv[13], ep[13], et[13];
        float Z = 0.0f, Zt = 0.0f;
        #pragma unroll
        for (int j = 0; j < 13; ++j) {            // no max-pass: inputs ~N(0,1)
            const float x = (j < L) ? P[base + j] : NEG_BIG;
            const float y = (j < L) ? T[base + j] : NEG_BIG;
            pv[j] = x;
            ep[j] = __expf(x);  Z  += ep[j];
            et[j] = __expf(y);  Zt += et[j];
        }
        const float logZ  = __logf(Z);
        const float rcpZ  = __builtin_amdgcn_rcpf(Z);
        const float rcpZt = __builtin_amdgcn_rcpf(Zt);

        float acc = 0.0f;
        #pragma unroll
        for (int j = 0; j < 13; ++j) {
            const float logp = pv[j] - logZ;                  // masked j -> -1e30
            const float p    = ep[j] * rcpZ;                  // masked j -> 0
            const float ca   = fmaxf(logp, LOGCLAMP);
            const float cb   = fmaxf(__logf(fmaxf(1.0f - p, 0.0f)), LOGCLAMP);
            const float t_   = et[j] * rcpZt;                 // masked j -> 0
            acc += cb + t_ * (ca - cb);                       // = t*ca + (1-t)*cb
        }
        const float per = valid ? (-acc) * w : 0.0f;          // kills tail garbage/NaN
        a0 += (c == 0) ? per : 0.0f;
        a1 += (c == 1) ? per : 0.0f;
        a2 += (c == 2) ? per : 0.0f;

        __syncthreads();   // vmcnt(0) drain: stage(t+1) landed; barrier
        cur ^= 1;
        ccur = cnext;
    }

    // ---- block reduction: wave shuffle -> LDS atomics -> 4 global atomics ----
    #pragma unroll
    for (int off = 32; off > 0; off >>= 1) {
        a0 += __shfl_down(a0, off, 64);
        a1 += __shfl_down(a1, off, 64);
        a2 += __shfl_down(a2, off, 64);
    }
    if ((tid & 63) == 0) {
        atomicAdd(&cls_sum[0], a0);
        atomicAdd(&cls_sum[1], a1);
        atomicAdd(&cls_sum[2], a2);
    }
    __syncthreads();
    if (tid == 0) {
        const float s0 = cls_sum[0], s1 = cls_sum[1], s2 = cls_sum[2];
        atomicAdd(&out[1], s0);
        atomicAdd(&out[2], s1);
        atomicAdd(&out[3], s2);
        atomicAdd(&out[0], (s0 + s1 + s2) * (1.0f / (float)BATCH));
    }
}

extern "C" void kernel_launch(void* const* d_in, const int* in_sizes, int n_in,
                              void* d_out, int out_size, void* d_ws, size_t ws_size,
                              hipStream_t stream) {
    const float* preds   = (const float*)d_in[0];
    const float* labels  = (const float*)d_in[1];
    const float* weights = (const float*)d_in[2];
    const int*   obj     = (const int*)d_in[3];
    float* out = (float*)d_out;

    hipMemsetAsync(out, 0, (size_t)out_size * sizeof(float), stream);
    adviser_loss_kernel<<<NBLK, TPB, 0, stream>>>(preds, labels, weights, obj, out);
}